// Round 1
// baseline (713.140 us; speedup 1.0000x reference)
//
#include <hip/hip_runtime.h>

#define N_NODES 100000
#define N_EDGES 1600000
#define IN_CH   165
#define SCAN_CHUNK 2048   // 256 threads * 8 elems
#define NB_SCAN ((N_NODES + SCAN_CHUNK - 1) / SCAN_CHUNK)

// ---------------- degree / norm ----------------
__global__ void count_kernel(const int* __restrict__ col, int* __restrict__ cnt, int E) {
    int i = blockIdx.x * blockDim.x + threadIdx.x;
    int stride = gridDim.x * blockDim.x;
    for (int e = i; e < E; e += stride) atomicAdd(&cnt[col[e]], 1);
}

__global__ void dis_kernel(const int* __restrict__ cnt, float* __restrict__ dis, int n) {
    int i = blockIdx.x * blockDim.x + threadIdx.x;
    if (i < n) dis[i] = rsqrtf((float)(cnt[i] + 1));   // +1 = self loop
}

// ---------------- exclusive scan (3 kernels) ----------------
__global__ void scan1_kernel(const int* __restrict__ cnt, int* __restrict__ off,
                             int* __restrict__ bsum, int n) {
    __shared__ int sh[256];
    int t = threadIdx.x;
    int base = blockIdx.x * SCAN_CHUNK + t * 8;
    int v[8];
    int run = 0;
    #pragma unroll
    for (int j = 0; j < 8; ++j) {
        int c = (base + j < n) ? cnt[base + j] : 0;
        v[j] = run; run += c;
    }
    sh[t] = run;
    __syncthreads();
    for (int o = 1; o < 256; o <<= 1) {
        int x = (t >= o) ? sh[t - o] : 0;
        __syncthreads();
        sh[t] += x;
        __syncthreads();
    }
    int prev = (t > 0) ? sh[t - 1] : 0;
    #pragma unroll
    for (int j = 0; j < 8; ++j)
        if (base + j < n) off[base + j] = prev + v[j];
    if (t == 255) bsum[blockIdx.x] = sh[255];
}

__global__ void scan2_kernel(int* bsum, int nb) {
    if (threadIdx.x == 0 && blockIdx.x == 0) {
        int run = 0;
        for (int i = 0; i < nb; ++i) { int c = bsum[i]; bsum[i] = run; run += c; }
    }
}

__global__ void scan3_kernel(int* __restrict__ off, const int* __restrict__ bsum,
                             int* __restrict__ cur, int n, int E) {
    int i = blockIdx.x * blockDim.x + threadIdx.x;
    if (i < n) {
        int o = off[i] + bsum[i / SCAN_CHUNK];
        off[i] = o;
        cur[i] = o;
    } else if (i == n) {
        off[n] = E;
    }
}

// ---------------- CSR scatter ----------------
__global__ void scatter_kernel(const int* __restrict__ row, const int* __restrict__ col,
                               int* __restrict__ cur, int* __restrict__ srt, int E) {
    int i = blockIdx.x * blockDim.x + threadIdx.x;
    int stride = gridDim.x * blockDim.x;
    for (int e = i; e < E; e += stride) {
        int c = col[e];
        int p = atomicAdd(&cur[c], 1);
        srt[p] = row[e];
    }
}

// ---------------- dense GEMM: M[n][NOUT] = X[n][KTOT] @ W[KTOT][NOUT] ----------------
// TX channel-groups of 4 (float4), TY=256/TX node groups, RN nodes/thread.
template<int NOUT, int KTOT, int KC, int TX, int RN>
__global__ void gemm_kernel(const float* __restrict__ X, const float* __restrict__ W,
                            float* __restrict__ M, int n_nodes) {
    constexpr int TY = 256 / TX;
    constexpr int NT = TY * RN;          // nodes per block
    __shared__ float xs[NT][KC + 1];
    __shared__ float ws[KC][NOUT];
    int t = threadIdx.x;
    int tx = t % TX, ty = t / TX;
    long node0 = (long)blockIdx.x * NT;

    float acc[RN][4];
    #pragma unroll
    for (int i = 0; i < RN; ++i)
        #pragma unroll
        for (int j = 0; j < 4; ++j) acc[i][j] = 0.f;

    for (int k0 = 0; k0 < KTOT; k0 += KC) {
        // stage x tile
        for (int i = t; i < NT * KC; i += 256) {
            int n = i / KC, k = i - n * KC;
            long node = node0 + n;
            xs[n][k] = (node < n_nodes) ? X[node * KTOT + k0 + k] : 0.f;
        }
        // stage W tile
        for (int i = t; i < KC * NOUT; i += 256) {
            int k = i / NOUT, c = i - k * NOUT;
            ws[k][c] = W[(size_t)(k0 + k) * NOUT + c];
        }
        __syncthreads();
        for (int k = 0; k < KC; ++k) {
            float4 b = *(const float4*)&ws[k][tx * 4];
            #pragma unroll
            for (int i = 0; i < RN; ++i) {
                float a = xs[ty * RN + i][k];
                acc[i][0] += a * b.x;
                acc[i][1] += a * b.y;
                acc[i][2] += a * b.z;
                acc[i][3] += a * b.w;
            }
        }
        __syncthreads();
    }
    #pragma unroll
    for (int i = 0; i < RN; ++i) {
        long node = node0 + ty * RN + i;
        if (node < n_nodes) {
            float4 r = make_float4(acc[i][0], acc[i][1], acc[i][2], acc[i][3]);
            *(float4*)&M[node * NOUT + tx * 4] = r;
        }
    }
}

// ---------------- aggregation layer 1: 128 ch, wave-per-node, bias+ReLU fused ----------------
__global__ void agg1_kernel(const float* __restrict__ m, const int* __restrict__ srt,
                            const int* __restrict__ off, const float* __restrict__ dis,
                            const float* __restrict__ b1, float* __restrict__ h1) {
    int wave = threadIdx.x >> 6;
    int lane = threadIdx.x & 63;
    int n = blockIdx.x * 4 + wave;
    if (n >= N_NODES) return;
    float dn = dis[n];
    const float2* mrow = (const float2*)(m + (size_t)n * 128);
    float2 a = mrow[lane];
    float accx = dn * a.x, accy = dn * a.y;
    int s0 = off[n], s1 = off[n + 1];
    for (int e = s0; e < s1; ++e) {
        int s = srt[e];
        float w = dis[s];
        float2 v = ((const float2*)(m + (size_t)s * 128))[lane];
        accx += w * v.x;
        accy += w * v.y;
    }
    float2 b = ((const float2*)b1)[lane];
    float rx = fmaxf(accx * dn + b.x, 0.f);
    float ry = fmaxf(accy * dn + b.y, 0.f);
    ((float2*)(h1 + (size_t)n * 128))[lane] = make_float2(rx, ry);
}

// ---------------- aggregation layer 2 + output GEMM (64 ch -> 2) ----------------
__global__ void agg2_kernel(const float* __restrict__ m, const int* __restrict__ srt,
                            const int* __restrict__ off, const float* __restrict__ dis,
                            const float* __restrict__ b2, const float* __restrict__ Wo,
                            const float* __restrict__ bo, float* __restrict__ out) {
    int wave = threadIdx.x >> 6;
    int lane = threadIdx.x & 63;
    int n = blockIdx.x * 4 + wave;
    if (n >= N_NODES) return;
    float dn = dis[n];
    float acc = dn * m[(size_t)n * 64 + lane];
    int s0 = off[n], s1 = off[n + 1];
    for (int e = s0; e < s1; ++e) {
        int s = srt[e];
        acc += dis[s] * m[(size_t)s * 64 + lane];
    }
    float v = fmaxf(acc * dn + b2[lane], 0.f);
    float p0 = v * Wo[lane * 2];
    float p1 = v * Wo[lane * 2 + 1];
    #pragma unroll
    for (int o = 32; o > 0; o >>= 1) {
        p0 += __shfl_xor(p0, o);
        p1 += __shfl_xor(p1, o);
    }
    if (lane == 0) {
        out[(size_t)n * 2]     = p0 + bo[0];
        out[(size_t)n * 2 + 1] = p1 + bo[1];
    }
}

// ---------------- launch ----------------
extern "C" void kernel_launch(void* const* d_in, const int* in_sizes, int n_in,
                              void* d_out, int out_size, void* d_ws, size_t ws_size,
                              hipStream_t stream) {
    const float* x  = (const float*)d_in[0];
    const int*   ei = (const int*)d_in[1];
    const int*   row = ei;
    const int*   col = ei + N_EDGES;
    const float* W1 = (const float*)d_in[2];
    const float* b1 = (const float*)d_in[3];
    const float* W2 = (const float*)d_in[4];
    const float* b2 = (const float*)d_in[5];
    const float* Wo = (const float*)d_in[6];
    const float* bo = (const float*)d_in[7];
    float* out = (float*)d_out;

    char* base = (char*)d_ws;
    auto alloc = [&](size_t bytes) {
        char* p = base;
        base += (bytes + 255) & ~(size_t)255;
        return p;
    };
    int*   cnt  = (int*)alloc((size_t)N_NODES * 4);
    int*   off  = (int*)alloc((size_t)(N_NODES + 1) * 4);
    int*   cur  = (int*)alloc((size_t)N_NODES * 4);
    float* dis  = (float*)alloc((size_t)N_NODES * 4);
    int*   bsum = (int*)alloc(256);
    int*   srt  = (int*)alloc((size_t)N_EDGES * 4);
    float* m    = (float*)alloc((size_t)N_NODES * 128 * 4);   // m1, reused as m2
    float* h1   = (float*)alloc((size_t)N_NODES * 128 * 4);

    hipMemsetAsync(cnt, 0, (size_t)N_NODES * 4, stream);
    count_kernel<<<1024, 256, 0, stream>>>(col, cnt, N_EDGES);
    dis_kernel<<<(N_NODES + 255) / 256, 256, 0, stream>>>(cnt, dis, N_NODES);
    scan1_kernel<<<NB_SCAN, 256, 0, stream>>>(cnt, off, bsum, N_NODES);
    scan2_kernel<<<1, 64, 0, stream>>>(bsum, NB_SCAN);
    scan3_kernel<<<(N_NODES + 256) / 256, 256, 0, stream>>>(off, bsum, cur, N_NODES, N_EDGES);
    scatter_kernel<<<1024, 256, 0, stream>>>(row, col, cur, srt, N_EDGES);

    // layer 1: m1 = x @ W1 ; h1 = relu(agg(m1) + b1)
    gemm_kernel<128, 165, 55, 32, 8><<<(N_NODES + 63) / 64, 256, 0, stream>>>(x, W1, m, N_NODES);
    agg1_kernel<<<(N_NODES + 3) / 4, 256, 0, stream>>>(m, srt, off, dis, b1, h1);

    // layer 2: m2 = h1 @ W2 ; h2 = relu(agg(m2) + b2) ; out = h2 @ Wo + bo (fused)
    gemm_kernel<64, 128, 64, 16, 4><<<(N_NODES + 63) / 64, 256, 0, stream>>>(h1, W2, m, N_NODES);
    agg2_kernel<<<(N_NODES + 3) / 4, 256, 0, stream>>>(m, srt, off, dis, b2, Wo, bo, out);
}

// Round 2
// 570.792 us; speedup vs baseline: 1.2494x; 1.2494x over previous
//
#include <hip/hip_runtime.h>

#define N_NODES 100000
#define N_EDGES 1600000
#define IN_CH   165
#define SCAN_CHUNK 2048   // 256 threads * 8 elems
#define NB_SCAN ((N_NODES + SCAN_CHUNK - 1) / SCAN_CHUNK)

// ---------------- degree / norm ----------------
__global__ void count_kernel(const int* __restrict__ col, int* __restrict__ cnt, int E) {
    int i = blockIdx.x * blockDim.x + threadIdx.x;
    int stride = gridDim.x * blockDim.x;
    for (int e = i; e < E; e += stride) atomicAdd(&cnt[col[e]], 1);
}

__global__ void dis_kernel(const int* __restrict__ cnt, float* __restrict__ dis, int n) {
    int i = blockIdx.x * blockDim.x + threadIdx.x;
    if (i < n) dis[i] = rsqrtf((float)(cnt[i] + 1));   // +1 = self loop
}

// ---------------- exclusive scan (3 kernels) ----------------
__global__ void scan1_kernel(const int* __restrict__ cnt, int* __restrict__ off,
                             int* __restrict__ bsum, int n) {
    __shared__ int sh[256];
    int t = threadIdx.x;
    int base = blockIdx.x * SCAN_CHUNK + t * 8;
    int v[8];
    int run = 0;
    #pragma unroll
    for (int j = 0; j < 8; ++j) {
        int c = (base + j < n) ? cnt[base + j] : 0;
        v[j] = run; run += c;
    }
    sh[t] = run;
    __syncthreads();
    for (int o = 1; o < 256; o <<= 1) {
        int x = (t >= o) ? sh[t - o] : 0;
        __syncthreads();
        sh[t] += x;
        __syncthreads();
    }
    int prev = (t > 0) ? sh[t - 1] : 0;
    #pragma unroll
    for (int j = 0; j < 8; ++j)
        if (base + j < n) off[base + j] = prev + v[j];
    if (t == 255) bsum[blockIdx.x] = sh[255];
}

// single-wave shuffle scan (NB_SCAN=49 <= 64)
__global__ void scan2_kernel(int* bsum, int nb) {
    int lane = threadIdx.x;
    int orig = (lane < nb) ? bsum[lane] : 0;
    int v = orig;
    #pragma unroll
    for (int o = 1; o < 64; o <<= 1) {
        int t = __shfl_up(v, o);
        if (lane >= o) v += t;
    }
    if (lane < nb) bsum[lane] = v - orig;   // exclusive
}

__global__ void scan3_kernel(int* __restrict__ off, const int* __restrict__ bsum,
                             int* __restrict__ cur, int n, int E) {
    int i = blockIdx.x * blockDim.x + threadIdx.x;
    if (i < n) {
        int o = off[i] + bsum[i / SCAN_CHUNK];
        off[i] = o;
        cur[i] = o;
    } else if (i == n) {
        off[n] = E;
    }
}

// ---------------- CSR scatter ----------------
__global__ void scatter_kernel(const int* __restrict__ row, const int* __restrict__ col,
                               int* __restrict__ cur, int* __restrict__ srt, int E) {
    int i = blockIdx.x * blockDim.x + threadIdx.x;
    int stride = gridDim.x * blockDim.x;
    for (int e = i; e < E; e += stride) {
        int c = col[e];
        int p = atomicAdd(&cur[c], 1);
        srt[p] = row[e];
    }
}

// ---------------- dense GEMM: M[n][NOUT] = dis[n] * (X[n][KTOT] @ W[KTOT][NOUT]) ----
template<int NOUT, int KTOT, int KC, int TX, int RN>
__global__ void gemm_kernel(const float* __restrict__ X, const float* __restrict__ W,
                            const float* __restrict__ dis, float* __restrict__ M,
                            int n_nodes) {
    constexpr int TY = 256 / TX;
    constexpr int NT = TY * RN;          // nodes per block
    __shared__ float xs[NT][KC + 1];
    __shared__ float ws[KC][NOUT];
    int t = threadIdx.x;
    int tx = t % TX, ty = t / TX;
    long node0 = (long)blockIdx.x * NT;

    float acc[RN][4];
    #pragma unroll
    for (int i = 0; i < RN; ++i)
        #pragma unroll
        for (int j = 0; j < 4; ++j) acc[i][j] = 0.f;

    for (int k0 = 0; k0 < KTOT; k0 += KC) {
        for (int i = t; i < NT * KC; i += 256) {
            int n = i / KC, k = i - n * KC;
            long node = node0 + n;
            xs[n][k] = (node < n_nodes) ? X[node * KTOT + k0 + k] : 0.f;
        }
        for (int i = t; i < KC * NOUT; i += 256) {
            int k = i / NOUT, c = i - k * NOUT;
            ws[k][c] = W[(size_t)(k0 + k) * NOUT + c];
        }
        __syncthreads();
        for (int k = 0; k < KC; ++k) {
            float4 b = *(const float4*)&ws[k][tx * 4];
            #pragma unroll
            for (int i = 0; i < RN; ++i) {
                float a = xs[ty * RN + i][k];
                acc[i][0] += a * b.x;
                acc[i][1] += a * b.y;
                acc[i][2] += a * b.z;
                acc[i][3] += a * b.w;
            }
        }
        __syncthreads();
    }
    #pragma unroll
    for (int i = 0; i < RN; ++i) {
        long node = node0 + ty * RN + i;
        if (node < n_nodes) {
            float d = dis[node];
            float4 r = make_float4(acc[i][0] * d, acc[i][1] * d,
                                   acc[i][2] * d, acc[i][3] * d);
            *(float4*)&M[node * NOUT + tx * 4] = r;
        }
    }
}

// ---------------- aggregation layer 1: 128 ch, wave-per-node ----------------
// ms is pre-scaled by dis[src]; out = relu(dn * (ms[n] + sum ms[src]) + b1)
__global__ void agg1_kernel(const float* __restrict__ ms, const int* __restrict__ srt,
                            const int* __restrict__ off, const float* __restrict__ dis,
                            const float* __restrict__ b1, float* __restrict__ h1) {
    int wave = threadIdx.x >> 6;
    int lane = threadIdx.x & 63;
    int n = blockIdx.x * 4 + wave;
    if (n >= N_NODES) return;
    float dn = dis[n];
    float2 a = ((const float2*)(ms + (size_t)n * 128))[lane];
    float accx = a.x, accy = a.y;
    int s0 = off[n], s1 = off[n + 1];
    for (int base = s0; base < s1; base += 64) {
        int sv = (base + lane < s1) ? srt[base + lane] : 0;
        int cnt = min(64, s1 - base);
        int j = 0;
        for (; j + 7 < cnt; j += 8) {
            float2 v0 = ((const float2*)(ms + (size_t)__builtin_amdgcn_readlane(sv, j + 0) * 128))[lane];
            float2 v1 = ((const float2*)(ms + (size_t)__builtin_amdgcn_readlane(sv, j + 1) * 128))[lane];
            float2 v2 = ((const float2*)(ms + (size_t)__builtin_amdgcn_readlane(sv, j + 2) * 128))[lane];
            float2 v3 = ((const float2*)(ms + (size_t)__builtin_amdgcn_readlane(sv, j + 3) * 128))[lane];
            float2 v4 = ((const float2*)(ms + (size_t)__builtin_amdgcn_readlane(sv, j + 4) * 128))[lane];
            float2 v5 = ((const float2*)(ms + (size_t)__builtin_amdgcn_readlane(sv, j + 5) * 128))[lane];
            float2 v6 = ((const float2*)(ms + (size_t)__builtin_amdgcn_readlane(sv, j + 6) * 128))[lane];
            float2 v7 = ((const float2*)(ms + (size_t)__builtin_amdgcn_readlane(sv, j + 7) * 128))[lane];
            accx += v0.x + v1.x + v2.x + v3.x + v4.x + v5.x + v6.x + v7.x;
            accy += v0.y + v1.y + v2.y + v3.y + v4.y + v5.y + v6.y + v7.y;
        }
        for (; j < cnt; ++j) {
            int s = __builtin_amdgcn_readlane(sv, j);
            float2 v = ((const float2*)(ms + (size_t)s * 128))[lane];
            accx += v.x; accy += v.y;
        }
    }
    float2 b = ((const float2*)b1)[lane];
    float rx = fmaxf(accx * dn + b.x, 0.f);
    float ry = fmaxf(accy * dn + b.y, 0.f);
    ((float2*)(h1 + (size_t)n * 128))[lane] = make_float2(rx, ry);
}

// ---------------- aggregation layer 2 (64 ch) + output GEMM (64 -> 2) ----------------
__global__ void agg2_kernel(const float* __restrict__ ms, const int* __restrict__ srt,
                            const int* __restrict__ off, const float* __restrict__ dis,
                            const float* __restrict__ b2, const float* __restrict__ Wo,
                            const float* __restrict__ bo, float* __restrict__ out) {
    int wave = threadIdx.x >> 6;
    int lane = threadIdx.x & 63;
    int n = blockIdx.x * 4 + wave;
    if (n >= N_NODES) return;
    float dn = dis[n];
    float acc = ms[(size_t)n * 64 + lane];
    int s0 = off[n], s1 = off[n + 1];
    for (int base = s0; base < s1; base += 64) {
        int sv = (base + lane < s1) ? srt[base + lane] : 0;
        int cnt = min(64, s1 - base);
        int j = 0;
        for (; j + 7 < cnt; j += 8) {
            float v0 = ms[(size_t)__builtin_amdgcn_readlane(sv, j + 0) * 64 + lane];
            float v1 = ms[(size_t)__builtin_amdgcn_readlane(sv, j + 1) * 64 + lane];
            float v2 = ms[(size_t)__builtin_amdgcn_readlane(sv, j + 2) * 64 + lane];
            float v3 = ms[(size_t)__builtin_amdgcn_readlane(sv, j + 3) * 64 + lane];
            float v4 = ms[(size_t)__builtin_amdgcn_readlane(sv, j + 4) * 64 + lane];
            float v5 = ms[(size_t)__builtin_amdgcn_readlane(sv, j + 5) * 64 + lane];
            float v6 = ms[(size_t)__builtin_amdgcn_readlane(sv, j + 6) * 64 + lane];
            float v7 = ms[(size_t)__builtin_amdgcn_readlane(sv, j + 7) * 64 + lane];
            acc += v0 + v1 + v2 + v3 + v4 + v5 + v6 + v7;
        }
        for (; j < cnt; ++j) {
            acc += ms[(size_t)__builtin_amdgcn_readlane(sv, j) * 64 + lane];
        }
    }
    float v = fmaxf(acc * dn + b2[lane], 0.f);
    float p0 = v * Wo[lane * 2];
    float p1 = v * Wo[lane * 2 + 1];
    #pragma unroll
    for (int o = 32; o > 0; o >>= 1) {
        p0 += __shfl_xor(p0, o);
        p1 += __shfl_xor(p1, o);
    }
    if (lane == 0) {
        out[(size_t)n * 2]     = p0 + bo[0];
        out[(size_t)n * 2 + 1] = p1 + bo[1];
    }
}

// ---------------- launch ----------------
extern "C" void kernel_launch(void* const* d_in, const int* in_sizes, int n_in,
                              void* d_out, int out_size, void* d_ws, size_t ws_size,
                              hipStream_t stream) {
    const float* x  = (const float*)d_in[0];
    const int*   ei = (const int*)d_in[1];
    const int*   row = ei;
    const int*   col = ei + N_EDGES;
    const float* W1 = (const float*)d_in[2];
    const float* b1 = (const float*)d_in[3];
    const float* W2 = (const float*)d_in[4];
    const float* b2 = (const float*)d_in[5];
    const float* Wo = (const float*)d_in[6];
    const float* bo = (const float*)d_in[7];
    float* out = (float*)d_out;

    char* base = (char*)d_ws;
    auto alloc = [&](size_t bytes) {
        char* p = base;
        base += (bytes + 255) & ~(size_t)255;
        return p;
    };
    int*   cnt  = (int*)alloc((size_t)N_NODES * 4);
    int*   off  = (int*)alloc((size_t)(N_NODES + 1) * 4);
    int*   cur  = (int*)alloc((size_t)N_NODES * 4);
    float* dis  = (float*)alloc((size_t)N_NODES * 4);
    int*   bsum = (int*)alloc(256);
    int*   srt  = (int*)alloc((size_t)N_EDGES * 4);
    float* m    = (float*)alloc((size_t)N_NODES * 128 * 4);   // m1, reused as m2
    float* h1   = (float*)alloc((size_t)N_NODES * 128 * 4);

    hipMemsetAsync(cnt, 0, (size_t)N_NODES * 4, stream);
    count_kernel<<<1024, 256, 0, stream>>>(col, cnt, N_EDGES);
    dis_kernel<<<(N_NODES + 255) / 256, 256, 0, stream>>>(cnt, dis, N_NODES);
    scan1_kernel<<<NB_SCAN, 256, 0, stream>>>(cnt, off, bsum, N_NODES);
    scan2_kernel<<<1, 64, 0, stream>>>(bsum, NB_SCAN);
    scan3_kernel<<<(N_NODES + 256) / 256, 256, 0, stream>>>(off, bsum, cur, N_NODES, N_EDGES);
    scatter_kernel<<<1024, 256, 0, stream>>>(row, col, cur, srt, N_EDGES);

    // layer 1: m = dis * (x @ W1) ; h1 = relu(dn*(m[n]+sum m[src]) + b1)
    gemm_kernel<128, 165, 55, 32, 8><<<(N_NODES + 63) / 64, 256, 0, stream>>>(x, W1, dis, m, N_NODES);
    agg1_kernel<<<(N_NODES + 3) / 4, 256, 0, stream>>>(m, srt, off, dis, b1, h1);

    // layer 2: m = dis * (h1 @ W2) ; fused agg + relu + output GEMM
    gemm_kernel<64, 128, 64, 16, 4><<<(N_NODES + 63) / 64, 256, 0, stream>>>(h1, W2, dis, m, N_NODES);
    agg2_kernel<<<(N_NODES + 3) / 4, 256, 0, stream>>>(m, srt, off, dis, b2, Wo, bo, out);
}